// Round 10
// baseline (306.407 us; speedup 1.0000x reference)
//
#include <hip/hip_runtime.h>
#include <math.h>

// Problem constants (fixed by the reference)
constexpr int Bb  = 2;
constexpr int Ss  = 2048;
constexpr int Dd  = 2048;
constexpr int Hh  = 16;
constexpr int DHd = 128;
constexpr int BS  = Bb * Ss;   // 4096
constexpr int NQKV = 2304;     // 2048 q + 128 k + 128 v

typedef __bf16 bf16x8 __attribute__((ext_vector_type(8)));
typedef float  f32x4  __attribute__((ext_vector_type(4)));

// fp32 -> bf16 (RNE), bit-level
static __device__ __forceinline__ unsigned short f2bf(float f) {
  union { float f; unsigned int u; } a; a.f = f;
  unsigned int u = a.u;
  unsigned int r = (u + 0x7fffu + ((u >> 16) & 1u)) >> 16;
  return (unsigned short)r;
}
static __device__ __forceinline__ float bf2f(unsigned short u) {
  union { unsigned int u; float f; } a; a.u = ((unsigned int)u) << 16;
  return a.f;
}
// pack two fp32 -> one dword of 2 bf16 (lo = first), HW RNE pack
static __device__ __forceinline__ int cvtpk(float lo, float hi) {
  int r;
  asm("v_cvt_pk_bf16_f32 %0, %1, %2" : "=v"(r) : "v"(lo), "v"(hi));
  return r;
}
static __device__ __forceinline__ f32x4 mfma16(bf16x8 a, bf16x8 b, f32x4 c) {
  return __builtin_amdgcn_mfma_f32_16x16x32_bf16(a, b, c, 0, 0, 0);
}

// ---------------------------------------------------------------------------
// cast_all: blocks [0,2048): grid-stride fp32->bf16 casts over 4,325,376
// float4 items: [qw | kvw | ow | x].  blocks [2048,2560): RoPE table.
// ---------------------------------------------------------------------------
constexpr int CAST_ITEMS = 4325376;   // total float4 elements
constexpr int CAST_BLOCKS = 2048;

__global__ __launch_bounds__(256) void cast_all(
    const float* __restrict__ qw, const float* __restrict__ kvw,
    const float* __restrict__ ow, const float* __restrict__ x,
    unsigned short* __restrict__ dst,
    float2* __restrict__ ctab)
{
  const int blk = blockIdx.x;
  if (blk >= CAST_BLOCKS) {                        // RoPE table fill
    const int id = (blk - CAST_BLOCKS) * 256 + threadIdx.x;  // 0..131071
    const int s = id >> 6, i = id & 63;
    const float invf = exp2f(-(float)i * (13.287712379549449f / 64.0f));
    const float ang = (float)s * invf;
    ctab[id] = make_float2(cosf(ang), sinf(ang));
    return;
  }
  for (int i = blk * 256 + threadIdx.x; i < CAST_ITEMS; i += CAST_BLOCKS * 256) {
    const float* src; int off;
    if (i < 1048576)      { src = qw;  off = 0; }
    else if (i < 1179648) { src = kvw; off = 1048576; }
    else if (i < 2228224) { src = ow;  off = 1179648; }
    else                  { src = x;   off = 2228224; }
    const float4 v = ((const float4*)src)[i - off];
    ushort4 o;
    o.x = f2bf(v.x); o.y = f2bf(v.y); o.z = f2bf(v.z); o.w = f2bf(v.w);
    ((ushort4*)dst)[i] = o;
  }
}

// ---------------------------------------------------------------------------
// bf16 MFMA GEMM: C[M][N] = A[M][K] @ Bw[N][K]^T + bias(col).
// 128x128 tile, BK=64 as TWO proven TK=32 sub-tiles per barrier-pair
// (halves the barrier-drain stall; LDS 32 KB keeps occupancy headroom).
// XCD-chunked block swizzle (T1): each XCD owns a contiguous n-major slab
// -> its 4-M-row A panel (2 MB) stays L2-resident, reused N/TN times.
// ---------------------------------------------------------------------------
#define TM 128
#define TN 128
#define TK 32

#define GLOAD16(gp, lp)                                                        \
  __builtin_amdgcn_global_load_lds(                                            \
      (const __attribute__((address_space(1))) void*)(gp),                     \
      (__attribute__((address_space(3))) void*)(lp), 16, 0, 0)

template <bool BF16OUT>
__global__ __launch_bounds__(256) void gemm_bt_mfma(
    const unsigned short* __restrict__ A,    // M x K bf16
    const unsigned short* __restrict__ Bw,   // N x K bf16
    const float* __restrict__ bias1,
    const float* __restrict__ bias2,
    int nsplit,
    void* __restrict__ Cv,                   // M x N (fp32 or bf16)
    int M, int N, int K)
{
  __shared__ unsigned short As[2][TM * TK];   // 2 x 8 KB
  __shared__ unsigned short Bs[2][TN * TK];   // 2 x 8 KB

  const int tid  = threadIdx.x;
  const int w    = tid >> 6;
  const int lane = tid & 63;

  // --- XCD-chunked swizzle (exact when nwg % 8 == 0; else identity)
  const int nbx  = N / TN;
  const int nwg  = (M / TM) * nbx;
  int flat = (int)blockIdx.y * nbx + (int)blockIdx.x;
  if ((nwg & 7) == 0)
    flat = (flat & 7) * (nwg >> 3) + (flat >> 3);
  const int m0 = (flat / nbx) * TM;
  const int n0 = (flat % nbx) * TN;

  const int wm   = (w >> 1) * 64;
  const int wn   = (w & 1) * 64;

  f32x4 acc[4][4];
#pragma unroll
  for (int i = 0; i < 4; i++)
#pragma unroll
    for (int j = 0; j < 4; j++) acc[i][j] = (f32x4){0.f, 0.f, 0.f, 0.f};

  const int srow = lane >> 2;
  const int scol = (lane & 3) * 8;
  const unsigned short* aG0 = A  + (size_t)(m0 +      w * 16 + srow) * K + scol;
  const unsigned short* aG1 = A  + (size_t)(m0 + 64 + w * 16 + srow) * K + scol;
  const unsigned short* bG0 = Bw + (size_t)(n0 +      w * 16 + srow) * K + scol;
  const unsigned short* bG1 = Bw + (size_t)(n0 + 64 + w * 16 + srow) * K + scol;
  const int aOff0 = (     w * 16) * TK;
  const int aOff1 = (64 + w * 16) * TK;

  const int fr = lane & 15;
  const int fk = (lane >> 4) * 8;

  for (int k0 = 0; k0 < K; k0 += 2 * TK) {
    __syncthreads();
#pragma unroll
    for (int s = 0; s < 2; s++) {
      const int kk = k0 + s * TK;
      GLOAD16(aG0 + kk, &As[s][aOff0]);
      GLOAD16(aG1 + kk, &As[s][aOff1]);
      GLOAD16(bG0 + kk, &Bs[s][aOff0]);
      GLOAD16(bG1 + kk, &Bs[s][aOff1]);
    }
    __syncthreads();

#pragma unroll
    for (int s = 0; s < 2; s++) {
      bf16x8 af[4], bfr[4];
#pragma unroll
      for (int i = 0; i < 4; i++)
        af[i] = *(const bf16x8*)&As[s][(wm + i * 16 + fr) * TK + fk];
#pragma unroll
      for (int j = 0; j < 4; j++)
        bfr[j] = *(const bf16x8*)&Bs[s][(wn + j * 16 + fr) * TK + fk];
#pragma unroll
      for (int i = 0; i < 4; i++)
#pragma unroll
        for (int j = 0; j < 4; j++)
          acc[i][j] = mfma16(af[i], bfr[j], acc[i][j]);
    }
  }

  const int er = (lane >> 4) * 4;
  const int ec = lane & 15;
#pragma unroll
  for (int j = 0; j < 4; j++) {
    const int col = n0 + wn + j * 16 + ec;
    const float bv = (col < nsplit) ? bias1[col] : bias2[col - nsplit];
#pragma unroll
    for (int i = 0; i < 4; i++) {
      const int rbase = m0 + wm + i * 16 + er;
#pragma unroll
      for (int r = 0; r < 4; r++) {
        const float v = acc[i][j][r] + bv;
        if constexpr (BF16OUT)
          ((unsigned short*)Cv)[(size_t)(rbase + r) * N + col] = f2bf(v);
        else
          ((float*)Cv)[(size_t)(rbase + r) * N + col] = v;
      }
    }
  }
}

// ---------------------------------------------------------------------------
// prep_kv: from QKV bf16 (B,S,2304) — k cols [2048,2176), v cols [2176,2304) —
// produce Kb (B,S,128) roped (table-driven) and Vt (B,128,S) transposed.
// 128 blocks x 32 s-rows.
// ---------------------------------------------------------------------------
__global__ __launch_bounds__(256) void prep_kv(
    const unsigned short* __restrict__ QKV,
    const float2* __restrict__ ctab,
    unsigned short* __restrict__ Kb,
    unsigned short* __restrict__ Vt)
{
  __shared__ unsigned short Vtile[32 * 136];   // [s_local][d], padded

  const int blk = blockIdx.x;          // b*64 + stile
  const int b   = blk >> 6;
  const int s0  = (blk & 63) * 32;
  const int t   = threadIdx.x;

  // --- rope K (cos/sin from table): 8 threads/row, 8 elems each
  {
    const int r = t >> 3, p = t & 7;
    const int row = blk * 32 + r;
    const int s = row & (Ss - 1);
    const unsigned short* src = QKV + (size_t)row * NQKV + 2048 + p * 8;
    const float2* ct = ctab + s * 64 + p * 8;
    union { uint4 v; unsigned short a[8]; } lo, hi, ol, oh;
    lo.v = *(const uint4*)src;
    hi.v = *(const uint4*)(src + 64);
#pragma unroll
    for (int e = 0; e < 8; e++) {
      const float2 cs = ct[e];
      const float l = bf2f(lo.a[e]), hh = bf2f(hi.a[e]);
      ol.a[e] = f2bf(l * cs.x - hh * cs.y);
      oh.a[e] = f2bf(hh * cs.x + l * cs.y);
    }
    unsigned short* dst = Kb + (size_t)row * 128 + p * 8;
    *(uint4*)dst        = ol.v;
    *(uint4*)(dst + 64) = oh.v;
  }

  // --- stage V into LDS, s-major (32 rows x 128 cols)
#pragma unroll
  for (int c = 0; c < 2; c++) {
    const int id = c * 256 + t;
    const int vr = id >> 4, cc = id & 15;
    *(uint4*)&Vtile[vr * 136 + cc * 8] =
        *(const uint4*)(QKV + (size_t)(blk * 32 + vr) * NQKV + 2176 + cc * 8);
  }
  __syncthreads();

  // --- write Vt rows: d = t>>1 (128 dhs), half = t&1, 16 keys each
  {
    const int d = t >> 1, half = t & 1;
    union { uint4 v[2]; unsigned short a[16]; } val;
#pragma unroll
    for (int kk = 0; kk < 16; kk++)
      val.a[kk] = Vtile[(half * 16 + kk) * 136 + d];
    unsigned short* dst = Vt + ((size_t)(b * 128 + d)) * Ss + s0 + half * 16;
    *(uint4*)dst       = val.v[0];
    *(uint4*)(dst + 8) = val.v[1];
  }
}

// ---------------------------------------------------------------------------
// flash_v13 (unchanged, proven 74.3-75.0 us): paired q-tiles, 128-key
// single-buffer, slot-XOR LDS, table Q-rope, VALU diet, 512 threads / 8 waves
// (wave w<4 -> A-subtile w, w>=4 -> B-subtile w-4; K/V staging split by role).
// ---------------------------------------------------------------------------
__global__ __launch_bounds__(512, 4) void flash_v13(
    const unsigned short* __restrict__ QKV,  // (B,S,2304), q RAW (rope here)
    const unsigned short* __restrict__ Kb,   // (B,S,128) roped
    const unsigned short* __restrict__ Vt,   // (B,128,S)
    const float2* __restrict__ ctab,         // (2048, 64) cos/sin
    unsigned short* __restrict__ attn)       // (B,S,2048) bf16
{
  __shared__ unsigned short Ks[4 * 128 * 32];  // panel kf: [key128][dh32], 32 KB
  __shared__ unsigned short Vs[4 * 128 * 32];  // panel ks2: [dh128][key32], 32 KB

  // --- decode: co-resident {c, c+256} -> complementary p
  const int g  = (int)blockIdx.x;          // 0..511
  const int lo = g & 255, hi = g >> 8;
  const int p  = hi ? (15 - (lo & 15)) : (lo & 15);
  const int hb = (lo >> 4) + 16 * hi;      // 0..31
  const int h  = hb & 15;
  const int b  = hb >> 4;

  const int qA0 = (31 - p) * 64;           // heavy tile base (>= 1024)
  const int qB0 = p * 64;                  // light tile base (< 1024)

  const int tid = threadIdx.x;
  const int w = tid >> 6, lane = tid & 63;
  const int lg = lane >> 4, lm = lane & 15;

  // wave role: w<4 -> tile A subtile w; w>=4 -> tile B subtile w-4
  const bool isA = (w < 4);
  const int sw = w & 3;
  const int qt0 = isA ? qA0 : qB0;
  const int qrow    = qt0 + sw * 16 + lm;
  const int qrow_lo = qt0 + sw * 16;
  const int qrow_hi = qt0 + sw * 16 + 15;

  // swizzled frag slot: row contributions >=16 vanish mod 4 -> lane-constant
  const int klg = lg ^ ((lm >> 1) & 3);

  const float sscale = 0.08838834764831845f * 1.4426950408889634f; // /sqrt(128)*log2e

  // --- Q frag with fused table RoPE, PRE-SCALED by sscale
  bf16x8 qf[4];
  {
    union U8 { bf16x8 v; unsigned short a[8]; };
    const unsigned short* qp =
        QKV + (size_t)(b * Ss + qrow) * NQKV + h * DHd + lg * 8;
    const float2* ct = ctab + qrow * 64 + lg * 8;
    U8 lo0, lo1, hi0, hi1, ol0, ol1, oh0, oh1;
    lo0.v = *(const bf16x8*)(qp);
    lo1.v = *(const bf16x8*)(qp + 32);
    hi0.v = *(const bf16x8*)(qp + 64);
    hi1.v = *(const bf16x8*)(qp + 96);
#pragma unroll
    for (int j = 0; j < 8; j++) {
      {
        const float2 cs = ct[j];                      // i = lg*8+j
        const float l = bf2f(lo0.a[j]), hh = bf2f(hi0.a[j]);
        ol0.a[j] = f2bf((l * cs.x - hh * cs.y) * sscale);
        oh0.a[j] = f2bf((hh * cs.x + l * cs.y) * sscale);
      }
      {
        const float2 cs = ct[32 + j];                 // i = 32+lg*8+j
        const float l = bf2f(lo1.a[j]), hh = bf2f(hi1.a[j]);
        ol1.a[j] = f2bf((l * cs.x - hh * cs.y) * sscale);
        oh1.a[j] = f2bf((hh * cs.x + l * cs.y) * sscale);
      }
    }
    qf[0] = ol0.v; qf[1] = ol1.v; qf[2] = oh0.v; qf[3] = oh1.v;
  }

  // O^T accumulator, C-layout: (dh = dt*16 + 4*lg + r, qrow = lm)
  f32x4 ot[8];
#pragma unroll
  for (int dt = 0; dt < 8; dt++) ot[dt] = (f32x4){0.f, 0.f, 0.f, 0.f};
  float lsum = 0.f;

  // staging lane addresses; global chunk permuted so linear LDS dest holds
  // the slot-swizzled layout: chunk(lane) = (lane&3) ^ ((lane>>3)&3)
  const int sr  = lane >> 2;                             // row-within-16
  const int sc8 = ((lane & 3) ^ ((lane >> 3) & 3)) * 8;  // swizzled 16B chunk
  // K stager (waves 0-3): panel w = dh w*32..+31, 128 keys (8 GLOADs)
  const unsigned short* kg =
      Kb + (size_t)b * Ss * 128 + (size_t)sr * 128 + (w & 3) * 32 + sc8;
  unsigned short* ksl = &Ks[(w & 3) * 4096];
  // V stager (waves 4-7): panel ks2 = w-4 (keys ks2*32..+31), dh 0..127
  const int vks = w & 3;
  const unsigned short* vg =
      Vt + (size_t)b * 128 * Ss + (size_t)sr * Ss + sc8;
  unsigned short* vsl = &Vs[vks * 4096];

  // transpose shuffle sources (C->B layout, within a 32-key half)
  const int addr0 = (2 * (lg & 1)) * 16 + lm;   // dwords 0,1
  const int addr1 = addr0 + 16;                 // dwords 2,3
  const bool sel_hi = (lg & 2) != 0;

  // one 32-key half: S^T tiles tA,tA+1 -> exp -> transpose -> PV on panel VsP
  auto half32 = [&](int keybase, int tA, const unsigned short* VsP,
                    bool needmask) {
    f32x4 s[2];
    s[0] = (f32x4){0.f, 0.f, 0.f, 0.f};
    s[1] = (f32x4){0.f, 0.f, 0.f, 0.f};
    __builtin_amdgcn_s_setprio(1);
#pragma unroll
    for (int kf = 0; kf < 4; kf++) {
      const bf16x8 k0 = *(const bf16x8*)&Ks[kf * 4096 + ((tA)     * 16 + lm) * 32 + klg * 8];
      const bf16x8 k1 = *(const bf16x8*)&Ks[kf * 4096 + ((tA + 1) * 16 + lm) * 32 + klg * 8];
      s[0] = mfma16(k0, qf[kf], s[0]);
      s[1] = mfma16(k1, qf[kf], s[1]);
    }
    __builtin_amdgcn_s_setprio(0);
    // exp2 (max-free, Q pre-scaled) + diagonal-only mask + pack
    int pk[2][2];
#pragma unroll
    for (int t = 0; t < 2; t++) {
      float pv[4];
#pragma unroll
      for (int r = 0; r < 4; r++) pv[r] = exp2f(s[t][r]);
      if (needmask) {
        const int kb = keybase + t * 16 + 4 * lg;
#pragma unroll
        for (int r = 0; r < 4; r++)
          if (kb + r > qrow) pv[r] = 0.f;
      }
#pragma unroll
      for (int r = 0; r < 4; r++) lsum += pv[r];
      pk[t][0] = cvtpk(pv[0], pv[1]);
      pk[t][1] = cvtpk(pv[2], pv[3]);
    }
    // C-layout -> B-layout transpose (8 bpermutes)
    union { int d[4]; bf16x8 v; } pb;
#pragma unroll
    for (int d = 0; d < 4; d++) {
      const int src = (d < 2) ? addr0 : addr1;
      const int v0 = __shfl(pk[0][d & 1], src);
      const int v1 = __shfl(pk[1][d & 1], src);
      pb.d[d] = sel_hi ? v1 : v0;
    }
    // O^T += V^T(32 keys) · P^T
    __builtin_amdgcn_s_setprio(1);
#pragma unroll
    for (int dt = 0; dt < 8; dt++) {
      const bf16x8 vfrag = *(const bf16x8*)&VsP[(dt * 16 + lm) * 32 + klg * 8];
      ot[dt] = mfma16(vfrag, pb.v, ot[dt]);
    }
    __builtin_amdgcn_s_setprio(0);
  };

  for (int j0 = 0; j0 <= qA0; j0 += 128) {
    __syncthreads();            // previous iteration's LDS readers done
    if (isA) {
      // stage K panel (w&3): keys j0..j0+127, dh (w&3)*32..+31
#pragma unroll
      for (int i = 0; i < 8; i++)
        GLOAD16(kg + (size_t)(j0 + i * 16) * 128, ksl + i * 512);
    } else {
      // stage V panel vks: dh 0..127, keys j0+vks*32..+31
#pragma unroll
      for (int i = 0; i < 8; i++)
        GLOAD16(vg + (size_t)(i * 16) * Ss + j0 + vks * 32, vsl + i * 512);
    }
    __syncthreads();            // vmcnt(0) drained before use

    // my subtile: process active 32-key halves
#pragma unroll
    for (int t32 = 0; t32 < 4; t32++) {
      const int kb = j0 + t32 * 32;
      if (kb <= qrow_hi)                      // wave-uniform
        half32(kb, t32 * 2, &Vs[t32 * 4096], kb + 31 > qrow_lo);
    }
  }

  // --- epilogue: reduce lsum over the 4 lg groups, normalize, store
  lsum += __shfl_xor(lsum, 16);
  lsum += __shfl_xor(lsum, 32);
  const float inv = 1.0f / lsum;
  unsigned short* dst =
      attn + (size_t)(b * Ss + qrow) * Dd + h * DHd + lg * 4;
#pragma unroll
  for (int dt = 0; dt < 8; dt++) {
    uint2 st;
    st.x = (unsigned int)cvtpk(ot[dt][0] * inv, ot[dt][1] * inv);
    st.y = (unsigned int)cvtpk(ot[dt][2] * inv, ot[dt][3] * inv);
    *(uint2*)(dst + dt * 16) = st;
  }
}

// ---------------------------------------------------------------------------
extern "C" void kernel_launch(void* const* d_in, const int* in_sizes, int n_in,
                              void* d_out, int out_size, void* d_ws, size_t ws_size,
                              hipStream_t stream) {
  const float* x   = (const float*)d_in[0];   // (B,S,D)
  const float* qw  = (const float*)d_in[1];   // (2048, 2048)
  const float* qb  = (const float*)d_in[2];
  const float* kvw = (const float*)d_in[3];   // (256, 2048)
  const float* kvb = (const float*)d_in[4];
  const float* ow  = (const float*)d_in[5];   // (2048, 2048)
  const float* ob  = (const float*)d_in[6];
  float* out = (float*)d_out;

  // workspace layout (bf16 elements):
  //   wqkv @ 0          (2304 x 2048)   qw rows 0-2047, kvw 2048-2303
  //   owb  @ 4,718,592  (2048 x 2048)
  //   xb   @ 8,912,896  (4096 x 2048)   -> reused as attn_b
  //   QKV  @ 17,301,504 (4096 x 2304)
  //   Kb   @ 26,738,688 (4096 x 128)
  //   Vt   @ 27,262,976 (2 x 128 x 2048)
  //   ctab @ 27,787,264 (2048 x 64 float2 = 1 MB)
  unsigned short* wsb    = (unsigned short*)d_ws;
  unsigned short* wqkv   = wsb;
  unsigned short* owb    = wsb + 4718592;
  unsigned short* xb     = wsb + 8912896;
  unsigned short* attn_b = xb;                 // alias: xb dead after QKV gemm
  unsigned short* QKV    = wsb + 17301504;
  unsigned short* Kb     = wsb + 26738688;
  unsigned short* Vt     = wsb + 27262976;
  float2*         ctab   = (float2*)(wsb + 27787264);

  // 1. all fp32->bf16 casts (grid-stride, 2048 blocks) + RoPE table
  cast_all<<<2560, 256, 0, stream>>>(qw, kvw, ow, x, wqkv, ctab);

  // 2. merged QKV projection: (4096 x 2304) = xb @ wqkv^T + [qb|kvb]
  gemm_bt_mfma<true><<<dim3(NQKV / TN, BS / TM), 256, 0, stream>>>(
      xb, wqkv, qb, kvb, 2048, QKV, BS, NQKV, Dd);

  // 3. K rope (table) + V transpose (128 blocks; Q rope fused into flash)
  prep_kv<<<BS / 32, 256, 0, stream>>>(QKV, ctab, Kb, Vt);

  // 4. flash attention (8-wave pair blocks: 4 waves/SIMD)
  flash_v13<<<512, 512, 0, stream>>>(QKV, Kb, Vt, ctab, attn_b);

  // 5. O projection: out = attn @ ow^T + ob (fp32 out)
  gemm_bt_mfma<false><<<dim3(Dd / TN, BS / TM), 256, 0, stream>>>(
      attn_b, owb, ob, ob, Dd, out, BS, Dd, Dd);
}

// Round 11
// 299.122 us; speedup vs baseline: 1.0244x; 1.0244x over previous
//
#include <hip/hip_runtime.h>
#include <math.h>

// Problem constants (fixed by the reference)
constexpr int Bb  = 2;
constexpr int Ss  = 2048;
constexpr int Dd  = 2048;
constexpr int Hh  = 16;
constexpr int DHd = 128;
constexpr int BS  = Bb * Ss;   // 4096
constexpr int NQKV = 2304;     // 2048 q + 128 k + 128 v

typedef __bf16 bf16x8 __attribute__((ext_vector_type(8)));
typedef float  f32x4  __attribute__((ext_vector_type(4)));

// fp32 -> bf16 (RNE), bit-level
static __device__ __forceinline__ unsigned short f2bf(float f) {
  union { float f; unsigned int u; } a; a.f = f;
  unsigned int u = a.u;
  unsigned int r = (u + 0x7fffu + ((u >> 16) & 1u)) >> 16;
  return (unsigned short)r;
}
static __device__ __forceinline__ float bf2f(unsigned short u) {
  union { unsigned int u; float f; } a; a.u = ((unsigned int)u) << 16;
  return a.f;
}
// pack two fp32 -> one dword of 2 bf16 (lo = first), HW RNE pack
static __device__ __forceinline__ int cvtpk(float lo, float hi) {
  int r;
  asm("v_cvt_pk_bf16_f32 %0, %1, %2" : "=v"(r) : "v"(lo), "v"(hi));
  return r;
}
static __device__ __forceinline__ f32x4 mfma16(bf16x8 a, bf16x8 b, f32x4 c) {
  return __builtin_amdgcn_mfma_f32_16x16x32_bf16(a, b, c, 0, 0, 0);
}

// ---------------------------------------------------------------------------
// cast_all: blocks [0,2048): grid-stride fp32->bf16 casts over 4,325,376
// float4 items: [qw | kvw | ow | x].  blocks [2048,2560): RoPE table.
// ---------------------------------------------------------------------------
constexpr int CAST_ITEMS = 4325376;   // total float4 elements
constexpr int CAST_BLOCKS = 2048;

__global__ __launch_bounds__(256) void cast_all(
    const float* __restrict__ qw, const float* __restrict__ kvw,
    const float* __restrict__ ow, const float* __restrict__ x,
    unsigned short* __restrict__ dst,
    float2* __restrict__ ctab)
{
  const int blk = blockIdx.x;
  if (blk >= CAST_BLOCKS) {                        // RoPE table fill
    const int id = (blk - CAST_BLOCKS) * 256 + threadIdx.x;  // 0..131071
    const int s = id >> 6, i = id & 63;
    const float invf = exp2f(-(float)i * (13.287712379549449f / 64.0f));
    const float ang = (float)s * invf;
    ctab[id] = make_float2(cosf(ang), sinf(ang));
    return;
  }
  for (int i = blk * 256 + threadIdx.x; i < CAST_ITEMS; i += CAST_BLOCKS * 256) {
    const float* src; int off;
    if (i < 1048576)      { src = qw;  off = 0; }
    else if (i < 1179648) { src = kvw; off = 1048576; }
    else if (i < 2228224) { src = ow;  off = 1179648; }
    else                  { src = x;   off = 2228224; }
    const float4 v = ((const float4*)src)[i - off];
    ushort4 o;
    o.x = f2bf(v.x); o.y = f2bf(v.y); o.z = f2bf(v.z); o.w = f2bf(v.w);
    ((ushort4*)dst)[i] = o;
  }
}

// ---------------------------------------------------------------------------
// bf16 MFMA GEMM: C[M][N] = A[M][K] @ Bw[N][K]^T + bias(col).
// PROVEN R8 body: 128x128 tile, BK=32, single As/Bs (16 KB), 256 threads,
// global_load_lds width-16 staging.  (R9's BK=64 regressed: −7 occupancy pts,
// schedule changes don't pay at this structure.)
// KEPT from R9: XCD-chunked block swizzle — FETCH_SIZE 89 -> 63.6 MB measured,
// schedule-neutral.
// ---------------------------------------------------------------------------
#define TM 128
#define TN 128
#define TK 32

#define GLOAD16(gp, lp)                                                        \
  __builtin_amdgcn_global_load_lds(                                            \
      (const __attribute__((address_space(1))) void*)(gp),                     \
      (__attribute__((address_space(3))) void*)(lp), 16, 0, 0)

template <bool BF16OUT>
__global__ __launch_bounds__(256) void gemm_bt_mfma(
    const unsigned short* __restrict__ A,    // M x K bf16
    const unsigned short* __restrict__ Bw,   // N x K bf16
    const float* __restrict__ bias1,
    const float* __restrict__ bias2,
    int nsplit,
    void* __restrict__ Cv,                   // M x N (fp32 or bf16)
    int M, int N, int K)
{
  __shared__ unsigned short As[TM * TK];   // 8 KB
  __shared__ unsigned short Bs[TN * TK];   // 8 KB

  const int tid  = threadIdx.x;
  const int w    = tid >> 6;
  const int lane = tid & 63;

  // --- XCD-chunked swizzle (exact when nwg % 8 == 0; else identity)
  const int nbx  = N / TN;
  const int nwg  = (M / TM) * nbx;
  int flat = (int)blockIdx.y * nbx + (int)blockIdx.x;
  if ((nwg & 7) == 0)
    flat = (flat & 7) * (nwg >> 3) + (flat >> 3);
  const int m0 = (flat / nbx) * TM;
  const int n0 = (flat % nbx) * TN;

  const int wm   = (w >> 1) * 64;
  const int wn   = (w & 1) * 64;

  f32x4 acc[4][4];
#pragma unroll
  for (int i = 0; i < 4; i++)
#pragma unroll
    for (int j = 0; j < 4; j++) acc[i][j] = (f32x4){0.f, 0.f, 0.f, 0.f};

  const int srow = lane >> 2;
  const int scol = (lane & 3) * 8;
  const unsigned short* aG0 = A  + (size_t)(m0 +      w * 16 + srow) * K + scol;
  const unsigned short* aG1 = A  + (size_t)(m0 + 64 + w * 16 + srow) * K + scol;
  const unsigned short* bG0 = Bw + (size_t)(n0 +      w * 16 + srow) * K + scol;
  const unsigned short* bG1 = Bw + (size_t)(n0 + 64 + w * 16 + srow) * K + scol;
  unsigned short* aL0 = &As[(     w * 16) * TK];
  unsigned short* aL1 = &As[(64 + w * 16) * TK];
  unsigned short* bL0 = &Bs[(     w * 16) * TK];
  unsigned short* bL1 = &Bs[(64 + w * 16) * TK];

  const int fr = lane & 15;
  const int fk = (lane >> 4) * 8;

  for (int k0 = 0; k0 < K; k0 += TK) {
    __syncthreads();
    GLOAD16(aG0 + k0, aL0);
    GLOAD16(aG1 + k0, aL1);
    GLOAD16(bG0 + k0, bL0);
    GLOAD16(bG1 + k0, bL1);
    __syncthreads();

    bf16x8 af[4], bfr[4];
#pragma unroll
    for (int i = 0; i < 4; i++)
      af[i] = *(const bf16x8*)&As[(wm + i * 16 + fr) * TK + fk];
#pragma unroll
    for (int j = 0; j < 4; j++)
      bfr[j] = *(const bf16x8*)&Bs[(wn + j * 16 + fr) * TK + fk];
#pragma unroll
    for (int i = 0; i < 4; i++)
#pragma unroll
      for (int j = 0; j < 4; j++)
        acc[i][j] = mfma16(af[i], bfr[j], acc[i][j]);
  }

  const int er = (lane >> 4) * 4;
  const int ec = lane & 15;
#pragma unroll
  for (int j = 0; j < 4; j++) {
    const int col = n0 + wn + j * 16 + ec;
    const float bv = (col < nsplit) ? bias1[col] : bias2[col - nsplit];
#pragma unroll
    for (int i = 0; i < 4; i++) {
      const int rbase = m0 + wm + i * 16 + er;
#pragma unroll
      for (int r = 0; r < 4; r++) {
        const float v = acc[i][j][r] + bv;
        if constexpr (BF16OUT)
          ((unsigned short*)Cv)[(size_t)(rbase + r) * N + col] = f2bf(v);
        else
          ((float*)Cv)[(size_t)(rbase + r) * N + col] = v;
      }
    }
  }
}

// ---------------------------------------------------------------------------
// prep_kv: from QKV bf16 (B,S,2304) — k cols [2048,2176), v cols [2176,2304) —
// produce Kb (B,S,128) roped (table-driven) and Vt (B,128,S) transposed.
// 128 blocks x 32 s-rows.
// ---------------------------------------------------------------------------
__global__ __launch_bounds__(256) void prep_kv(
    const unsigned short* __restrict__ QKV,
    const float2* __restrict__ ctab,
    unsigned short* __restrict__ Kb,
    unsigned short* __restrict__ Vt)
{
  __shared__ unsigned short Vtile[32 * 136];   // [s_local][d], padded

  const int blk = blockIdx.x;          // b*64 + stile
  const int b   = blk >> 6;
  const int s0  = (blk & 63) * 32;
  const int t   = threadIdx.x;

  // --- rope K (cos/sin from table): 8 threads/row, 8 elems each
  {
    const int r = t >> 3, p = t & 7;
    const int row = blk * 32 + r;
    const int s = row & (Ss - 1);
    const unsigned short* src = QKV + (size_t)row * NQKV + 2048 + p * 8;
    const float2* ct = ctab + s * 64 + p * 8;
    union { uint4 v; unsigned short a[8]; } lo, hi, ol, oh;
    lo.v = *(const uint4*)src;
    hi.v = *(const uint4*)(src + 64);
#pragma unroll
    for (int e = 0; e < 8; e++) {
      const float2 cs = ct[e];
      const float l = bf2f(lo.a[e]), hh = bf2f(hi.a[e]);
      ol.a[e] = f2bf(l * cs.x - hh * cs.y);
      oh.a[e] = f2bf(hh * cs.x + l * cs.y);
    }
    unsigned short* dst = Kb + (size_t)row * 128 + p * 8;
    *(uint4*)dst        = ol.v;
    *(uint4*)(dst + 64) = oh.v;
  }

  // --- stage V into LDS, s-major (32 rows x 128 cols)
#pragma unroll
  for (int c = 0; c < 2; c++) {
    const int id = c * 256 + t;
    const int vr = id >> 4, cc = id & 15;
    *(uint4*)&Vtile[vr * 136 + cc * 8] =
        *(const uint4*)(QKV + (size_t)(blk * 32 + vr) * NQKV + 2176 + cc * 8);
  }
  __syncthreads();

  // --- write Vt rows: d = t>>1 (128 dhs), half = t&1, 16 keys each
  {
    const int d = t >> 1, half = t & 1;
    union { uint4 v[2]; unsigned short a[16]; } val;
#pragma unroll
    for (int kk = 0; kk < 16; kk++)
      val.a[kk] = Vtile[(half * 16 + kk) * 136 + d];
    unsigned short* dst = Vt + ((size_t)(b * 128 + d)) * Ss + s0 + half * 16;
    *(uint4*)dst       = val.v[0];
    *(uint4*)(dst + 8) = val.v[1];
  }
}

// ---------------------------------------------------------------------------
// flash_v13 (unchanged, proven 74.3-75.0 us): paired q-tiles, 128-key
// single-buffer, slot-XOR LDS, table Q-rope, VALU diet, 512 threads / 8 waves
// (wave w<4 -> A-subtile w, w>=4 -> B-subtile w-4; K/V staging split by role).
// ---------------------------------------------------------------------------
__global__ __launch_bounds__(512, 4) void flash_v13(
    const unsigned short* __restrict__ QKV,  // (B,S,2304), q RAW (rope here)
    const unsigned short* __restrict__ Kb,   // (B,S,128) roped
    const unsigned short* __restrict__ Vt,   // (B,128,S)
    const float2* __restrict__ ctab,         // (2048, 64) cos/sin
    unsigned short* __restrict__ attn)       // (B,S,2048) bf16
{
  __shared__ unsigned short Ks[4 * 128 * 32];  // panel kf: [key128][dh32], 32 KB
  __shared__ unsigned short Vs[4 * 128 * 32];  // panel ks2: [dh128][key32], 32 KB

  // --- decode: co-resident {c, c+256} -> complementary p
  const int g  = (int)blockIdx.x;          // 0..511
  const int lo = g & 255, hi = g >> 8;
  const int p  = hi ? (15 - (lo & 15)) : (lo & 15);
  const int hb = (lo >> 4) + 16 * hi;      // 0..31
  const int h  = hb & 15;
  const int b  = hb >> 4;

  const int qA0 = (31 - p) * 64;           // heavy tile base (>= 1024)
  const int qB0 = p * 64;                  // light tile base (< 1024)

  const int tid = threadIdx.x;
  const int w = tid >> 6, lane = tid & 63;
  const int lg = lane >> 4, lm = lane & 15;

  // wave role: w<4 -> tile A subtile w; w>=4 -> tile B subtile w-4
  const bool isA = (w < 4);
  const int sw = w & 3;
  const int qt0 = isA ? qA0 : qB0;
  const int qrow    = qt0 + sw * 16 + lm;
  const int qrow_lo = qt0 + sw * 16;
  const int qrow_hi = qt0 + sw * 16 + 15;

  // swizzled frag slot: row contributions >=16 vanish mod 4 -> lane-constant
  const int klg = lg ^ ((lm >> 1) & 3);

  const float sscale = 0.08838834764831845f * 1.4426950408889634f; // /sqrt(128)*log2e

  // --- Q frag with fused table RoPE, PRE-SCALED by sscale
  bf16x8 qf[4];
  {
    union U8 { bf16x8 v; unsigned short a[8]; };
    const unsigned short* qp =
        QKV + (size_t)(b * Ss + qrow) * NQKV + h * DHd + lg * 8;
    const float2* ct = ctab + qrow * 64 + lg * 8;
    U8 lo0, lo1, hi0, hi1, ol0, ol1, oh0, oh1;
    lo0.v = *(const bf16x8*)(qp);
    lo1.v = *(const bf16x8*)(qp + 32);
    hi0.v = *(const bf16x8*)(qp + 64);
    hi1.v = *(const bf16x8*)(qp + 96);
#pragma unroll
    for (int j = 0; j < 8; j++) {
      {
        const float2 cs = ct[j];                      // i = lg*8+j
        const float l = bf2f(lo0.a[j]), hh = bf2f(hi0.a[j]);
        ol0.a[j] = f2bf((l * cs.x - hh * cs.y) * sscale);
        oh0.a[j] = f2bf((hh * cs.x + l * cs.y) * sscale);
      }
      {
        const float2 cs = ct[32 + j];                 // i = 32+lg*8+j
        const float l = bf2f(lo1.a[j]), hh = bf2f(hi1.a[j]);
        ol1.a[j] = f2bf((l * cs.x - hh * cs.y) * sscale);
        oh1.a[j] = f2bf((hh * cs.x + l * cs.y) * sscale);
      }
    }
    qf[0] = ol0.v; qf[1] = ol1.v; qf[2] = oh0.v; qf[3] = oh1.v;
  }

  // O^T accumulator, C-layout: (dh = dt*16 + 4*lg + r, qrow = lm)
  f32x4 ot[8];
#pragma unroll
  for (int dt = 0; dt < 8; dt++) ot[dt] = (f32x4){0.f, 0.f, 0.f, 0.f};
  float lsum = 0.f;

  // staging lane addresses; global chunk permuted so linear LDS dest holds
  // the slot-swizzled layout: chunk(lane) = (lane&3) ^ ((lane>>3)&3)
  const int sr  = lane >> 2;                             // row-within-16
  const int sc8 = ((lane & 3) ^ ((lane >> 3) & 3)) * 8;  // swizzled 16B chunk
  // K stager (waves 0-3): panel w = dh w*32..+31, 128 keys (8 GLOADs)
  const unsigned short* kg =
      Kb + (size_t)b * Ss * 128 + (size_t)sr * 128 + (w & 3) * 32 + sc8;
  unsigned short* ksl = &Ks[(w & 3) * 4096];
  // V stager (waves 4-7): panel ks2 = w-4 (keys ks2*32..+31), dh 0..127
  const int vks = w & 3;
  const unsigned short* vg =
      Vt + (size_t)b * 128 * Ss + (size_t)sr * Ss + sc8;
  unsigned short* vsl = &Vs[vks * 4096];

  // transpose shuffle sources (C->B layout, within a 32-key half)
  const int addr0 = (2 * (lg & 1)) * 16 + lm;   // dwords 0,1
  const int addr1 = addr0 + 16;                 // dwords 2,3
  const bool sel_hi = (lg & 2) != 0;

  // one 32-key half: S^T tiles tA,tA+1 -> exp -> transpose -> PV on panel VsP
  auto half32 = [&](int keybase, int tA, const unsigned short* VsP,
                    bool needmask) {
    f32x4 s[2];
    s[0] = (f32x4){0.f, 0.f, 0.f, 0.f};
    s[1] = (f32x4){0.f, 0.f, 0.f, 0.f};
    __builtin_amdgcn_s_setprio(1);
#pragma unroll
    for (int kf = 0; kf < 4; kf++) {
      const bf16x8 k0 = *(const bf16x8*)&Ks[kf * 4096 + ((tA)     * 16 + lm) * 32 + klg * 8];
      const bf16x8 k1 = *(const bf16x8*)&Ks[kf * 4096 + ((tA + 1) * 16 + lm) * 32 + klg * 8];
      s[0] = mfma16(k0, qf[kf], s[0]);
      s[1] = mfma16(k1, qf[kf], s[1]);
    }
    __builtin_amdgcn_s_setprio(0);
    // exp2 (max-free, Q pre-scaled) + diagonal-only mask + pack
    int pk[2][2];
#pragma unroll
    for (int t = 0; t < 2; t++) {
      float pv[4];
#pragma unroll
      for (int r = 0; r < 4; r++) pv[r] = exp2f(s[t][r]);
      if (needmask) {
        const int kb = keybase + t * 16 + 4 * lg;
#pragma unroll
        for (int r = 0; r < 4; r++)
          if (kb + r > qrow) pv[r] = 0.f;
      }
#pragma unroll
      for (int r = 0; r < 4; r++) lsum += pv[r];
      pk[t][0] = cvtpk(pv[0], pv[1]);
      pk[t][1] = cvtpk(pv[2], pv[3]);
    }
    // C-layout -> B-layout transpose (8 bpermutes)
    union { int d[4]; bf16x8 v; } pb;
#pragma unroll
    for (int d = 0; d < 4; d++) {
      const int src = (d < 2) ? addr0 : addr1;
      const int v0 = __shfl(pk[0][d & 1], src);
      const int v1 = __shfl(pk[1][d & 1], src);
      pb.d[d] = sel_hi ? v1 : v0;
    }
    // O^T += V^T(32 keys) · P^T
    __builtin_amdgcn_s_setprio(1);
#pragma unroll
    for (int dt = 0; dt < 8; dt++) {
      const bf16x8 vfrag = *(const bf16x8*)&VsP[(dt * 16 + lm) * 32 + klg * 8];
      ot[dt] = mfma16(vfrag, pb.v, ot[dt]);
    }
    __builtin_amdgcn_s_setprio(0);
  };

  for (int j0 = 0; j0 <= qA0; j0 += 128) {
    __syncthreads();            // previous iteration's LDS readers done
    if (isA) {
      // stage K panel (w&3): keys j0..j0+127, dh (w&3)*32..+31
#pragma unroll
      for (int i = 0; i < 8; i++)
        GLOAD16(kg + (size_t)(j0 + i * 16) * 128, ksl + i * 512);
    } else {
      // stage V panel vks: dh 0..127, keys j0+vks*32..+31
#pragma unroll
      for (int i = 0; i < 8; i++)
        GLOAD16(vg + (size_t)(i * 16) * Ss + j0 + vks * 32, vsl + i * 512);
    }
    __syncthreads();            // vmcnt(0) drained before use

    // my subtile: process active 32-key halves
#pragma unroll
    for (int t32 = 0; t32 < 4; t32++) {
      const int kb = j0 + t32 * 32;
      if (kb <= qrow_hi)                      // wave-uniform
        half32(kb, t32 * 2, &Vs[t32 * 4096], kb + 31 > qrow_lo);
    }
  }

  // --- epilogue: reduce lsum over the 4 lg groups, normalize, store
  lsum += __shfl_xor(lsum, 16);
  lsum += __shfl_xor(lsum, 32);
  const float inv = 1.0f / lsum;
  unsigned short* dst =
      attn + (size_t)(b * Ss + qrow) * Dd + h * DHd + lg * 4;
#pragma unroll
  for (int dt = 0; dt < 8; dt++) {
    uint2 st;
    st.x = (unsigned int)cvtpk(ot[dt][0] * inv, ot[dt][1] * inv);
    st.y = (unsigned int)cvtpk(ot[dt][2] * inv, ot[dt][3] * inv);
    *(uint2*)(dst + dt * 16) = st;
  }
}

// ---------------------------------------------------------------------------
extern "C" void kernel_launch(void* const* d_in, const int* in_sizes, int n_in,
                              void* d_out, int out_size, void* d_ws, size_t ws_size,
                              hipStream_t stream) {
  const float* x   = (const float*)d_in[0];   // (B,S,D)
  const float* qw  = (const float*)d_in[1];   // (2048, 2048)
  const float* qb  = (const float*)d_in[2];
  const float* kvw = (const float*)d_in[3];   // (256, 2048)
  const float* kvb = (const float*)d_in[4];
  const float* ow  = (const float*)d_in[5];   // (2048, 2048)
  const float* ob  = (const float*)d_in[6];
  float* out = (float*)d_out;

  // workspace layout (bf16 elements):
  //   wqkv @ 0          (2304 x 2048)   qw rows 0-2047, kvw 2048-2303
  //   owb  @ 4,718,592  (2048 x 2048)
  //   xb   @ 8,912,896  (4096 x 2048)   -> reused as attn_b
  //   QKV  @ 17,301,504 (4096 x 2304)
  //   Kb   @ 26,738,688 (4096 x 128)
  //   Vt   @ 27,262,976 (2 x 128 x 2048)
  //   ctab @ 27,787,264 (2048 x 64 float2 = 1 MB)
  unsigned short* wsb    = (unsigned short*)d_ws;
  unsigned short* wqkv   = wsb;
  unsigned short* owb    = wsb + 4718592;
  unsigned short* xb     = wsb + 8912896;
  unsigned short* attn_b = xb;                 // alias: xb dead after QKV gemm
  unsigned short* QKV    = wsb + 17301504;
  unsigned short* Kb     = wsb + 26738688;
  unsigned short* Vt     = wsb + 27262976;
  float2*         ctab   = (float2*)(wsb + 27787264);

  // 1. all fp32->bf16 casts (grid-stride, 2048 blocks) + RoPE table
  cast_all<<<2560, 256, 0, stream>>>(qw, kvw, ow, x, wqkv, ctab);

  // 2. merged QKV projection: (4096 x 2304) = xb @ wqkv^T + [qb|kvb]
  gemm_bt_mfma<true><<<dim3(NQKV / TN, BS / TM), 256, 0, stream>>>(
      xb, wqkv, qb, kvb, 2048, QKV, BS, NQKV, Dd);

  // 3. K rope (table) + V transpose (128 blocks; Q rope fused into flash)
  prep_kv<<<BS / 32, 256, 0, stream>>>(QKV, ctab, Kb, Vt);

  // 4. flash attention (8-wave pair blocks: 4 waves/SIMD)
  flash_v13<<<512, 512, 0, stream>>>(QKV, Kb, Vt, ctab, attn_b);

  // 5. O projection: out = attn @ ow^T + ob (fp32 out)
  gemm_bt_mfma<false><<<dim3(Dd / TN, BS / TM), 256, 0, stream>>>(
      attn_b, owb, ob, ob, Dd, out, BS, Dd, Dd);
}

// Round 12
// 277.175 us; speedup vs baseline: 1.1055x; 1.0792x over previous
//
#include <hip/hip_runtime.h>
#include <math.h>

// Problem constants (fixed by the reference)
constexpr int Bb  = 2;
constexpr int Ss  = 2048;
constexpr int Dd  = 2048;
constexpr int Hh  = 16;
constexpr int DHd = 128;
constexpr int BS  = Bb * Ss;   // 4096
constexpr int NQKV = 2304;     // 2048 q + 128 k + 128 v

typedef __bf16 bf16x8 __attribute__((ext_vector_type(8)));
typedef float  f32x4  __attribute__((ext_vector_type(4)));

// fp32 -> bf16 (RNE), bit-level
static __device__ __forceinline__ unsigned short f2bf(float f) {
  union { float f; unsigned int u; } a; a.f = f;
  unsigned int u = a.u;
  unsigned int r = (u + 0x7fffu + ((u >> 16) & 1u)) >> 16;
  return (unsigned short)r;
}
static __device__ __forceinline__ float bf2f(unsigned short u) {
  union { unsigned int u; float f; } a; a.u = ((unsigned int)u) << 16;
  return a.f;
}
// pack two fp32 -> one dword of 2 bf16 (lo = first), HW RNE pack
static __device__ __forceinline__ int cvtpk(float lo, float hi) {
  int r;
  asm("v_cvt_pk_bf16_f32 %0, %1, %2" : "=v"(r) : "v"(lo), "v"(hi));
  return r;
}
static __device__ __forceinline__ f32x4 mfma16(bf16x8 a, bf16x8 b, f32x4 c) {
  return __builtin_amdgcn_mfma_f32_16x16x32_bf16(a, b, c, 0, 0, 0);
}

// ---------------------------------------------------------------------------
// cast_all: blocks [0,2048): grid-stride fp32->bf16 casts over 4,325,376
// float4 items: [qw | kvw | ow | x].  blocks [2048,2560): RoPE table.
// ---------------------------------------------------------------------------
constexpr int CAST_ITEMS = 4325376;   // total float4 elements
constexpr int CAST_BLOCKS = 2048;

__global__ __launch_bounds__(256) void cast_all(
    const float* __restrict__ qw, const float* __restrict__ kvw,
    const float* __restrict__ ow, const float* __restrict__ x,
    unsigned short* __restrict__ dst,
    float2* __restrict__ ctab)
{
  const int blk = blockIdx.x;
  if (blk >= CAST_BLOCKS) {                        // RoPE table fill
    const int id = (blk - CAST_BLOCKS) * 256 + threadIdx.x;  // 0..131071
    const int s = id >> 6, i = id & 63;
    const float invf = exp2f(-(float)i * (13.287712379549449f / 64.0f));
    const float ang = (float)s * invf;
    ctab[id] = make_float2(cosf(ang), sinf(ang));
    return;
  }
  for (int i = blk * 256 + threadIdx.x; i < CAST_ITEMS; i += CAST_BLOCKS * 256) {
    const float* src; int off;
    if (i < 1048576)      { src = qw;  off = 0; }
    else if (i < 1179648) { src = kvw; off = 1048576; }
    else if (i < 2228224) { src = ow;  off = 1179648; }
    else                  { src = x;   off = 2228224; }
    const float4 v = ((const float4*)src)[i - off];
    ushort4 o;
    o.x = f2bf(v.x); o.y = f2bf(v.y); o.z = f2bf(v.z); o.w = f2bf(v.w);
    ((ushort4*)dst)[i] = o;
  }
}

// ---------------------------------------------------------------------------
// bf16 MFMA GEMM: C[M][N] = A[M][K] @ Bw[N][K]^T + bias(col).
// Same proven 128x128 tile / BK=32 / 16 KB LDS image / staging pattern /
// XCD-chunked swizzle as R10 — but 512 THREADS / 8 WAVES: wave (wr=w&3,
// wc=w>>2) computes a 32x64 sub-tile (acc[2][4]).  GEMM was grid-limited at
// ~2.25 waves/SIMD (Occupancy 19%); this doubles TLP at identical data
// layout (the same transform as flash R7's win).  Staging: waves 0-3 stage
// A row-blocks 2w,2w+1; waves 4-7 stage B likewise (16 x 1KB as before).
// ---------------------------------------------------------------------------
#define TM 128
#define TN 128
#define TK 32

#define GLOAD16(gp, lp)                                                        \
  __builtin_amdgcn_global_load_lds(                                            \
      (const __attribute__((address_space(1))) void*)(gp),                     \
      (__attribute__((address_space(3))) void*)(lp), 16, 0, 0)

template <bool BF16OUT>
__global__ __launch_bounds__(512, 4) void gemm_bt_mfma(
    const unsigned short* __restrict__ A,    // M x K bf16
    const unsigned short* __restrict__ Bw,   // N x K bf16
    const float* __restrict__ bias1,
    const float* __restrict__ bias2,
    int nsplit,
    void* __restrict__ Cv,                   // M x N (fp32 or bf16)
    int M, int N, int K)
{
  __shared__ unsigned short As[TM * TK];   // 8 KB
  __shared__ unsigned short Bs[TN * TK];   // 8 KB

  const int tid  = threadIdx.x;
  const int w    = tid >> 6;               // 0..7
  const int lane = tid & 63;

  // --- XCD-chunked swizzle (exact when nwg % 8 == 0; else identity)
  const int nbx  = N / TN;
  const int nwg  = (M / TM) * nbx;
  int flat = (int)blockIdx.y * nbx + (int)blockIdx.x;
  if ((nwg & 7) == 0)
    flat = (flat & 7) * (nwg >> 3) + (flat >> 3);
  const int m0 = (flat / nbx) * TM;
  const int n0 = (flat % nbx) * TN;

  const int wr = w & 3;                    // row-wave: 32-row strip
  const int wc = w >> 2;                   // col-wave: 64-col strip

  f32x4 acc[2][4];
#pragma unroll
  for (int i = 0; i < 2; i++)
#pragma unroll
    for (int j = 0; j < 4; j++) acc[i][j] = (f32x4){0.f, 0.f, 0.f, 0.f};

  // staging: wave w stages row-blocks 2*(w&3), 2*(w&3)+1 of A (w<4) or B.
  const int srow = lane >> 2;
  const int scol = (lane & 3) * 8;
  const int rb0 = 2 * (w & 3) * 16;        // first staged row
  const unsigned short* gSrc = (w < 4) ? A : Bw;
  const int gBase = (w < 4) ? m0 : n0;
  const unsigned short* g0 = gSrc + (size_t)(gBase + rb0 +      srow) * K + scol;
  const unsigned short* g1 = gSrc + (size_t)(gBase + rb0 + 16 + srow) * K + scol;
  unsigned short* lBuf = (w < 4) ? As : Bs;
  unsigned short* l0 = &lBuf[(rb0     ) * TK];
  unsigned short* l1 = &lBuf[(rb0 + 16) * TK];

  const int fr = lane & 15;
  const int fk = (lane >> 4) * 8;

  for (int k0 = 0; k0 < K; k0 += TK) {
    __syncthreads();
    GLOAD16(g0 + k0, l0);
    GLOAD16(g1 + k0, l1);
    __syncthreads();

    bf16x8 af[2], bfr[4];
#pragma unroll
    for (int i = 0; i < 2; i++)
      af[i] = *(const bf16x8*)&As[(wr * 32 + i * 16 + fr) * TK + fk];
#pragma unroll
    for (int j = 0; j < 4; j++)
      bfr[j] = *(const bf16x8*)&Bs[(wc * 64 + j * 16 + fr) * TK + fk];
#pragma unroll
    for (int i = 0; i < 2; i++)
#pragma unroll
      for (int j = 0; j < 4; j++)
        acc[i][j] = mfma16(af[i], bfr[j], acc[i][j]);
  }

  const int er = (lane >> 4) * 4;
  const int ec = lane & 15;
#pragma unroll
  for (int j = 0; j < 4; j++) {
    const int col = n0 + wc * 64 + j * 16 + ec;
    const float bv = (col < nsplit) ? bias1[col] : bias2[col - nsplit];
#pragma unroll
    for (int i = 0; i < 2; i++) {
      const int rbase = m0 + wr * 32 + i * 16 + er;
#pragma unroll
      for (int r = 0; r < 4; r++) {
        const float v = acc[i][j][r] + bv;
        if constexpr (BF16OUT)
          ((unsigned short*)Cv)[(size_t)(rbase + r) * N + col] = f2bf(v);
        else
          ((float*)Cv)[(size_t)(rbase + r) * N + col] = v;
      }
    }
  }
}

// ---------------------------------------------------------------------------
// prep_kv: from QKV bf16 (B,S,2304) — k cols [2048,2176), v cols [2176,2304) —
// produce Kb (B,S,128) roped (table-driven) and Vt (B,128,S) transposed.
// 128 blocks x 32 s-rows.
// ---------------------------------------------------------------------------
__global__ __launch_bounds__(256) void prep_kv(
    const unsigned short* __restrict__ QKV,
    const float2* __restrict__ ctab,
    unsigned short* __restrict__ Kb,
    unsigned short* __restrict__ Vt)
{
  __shared__ unsigned short Vtile[32 * 136];   // [s_local][d], padded

  const int blk = blockIdx.x;          // b*64 + stile
  const int b   = blk >> 6;
  const int s0  = (blk & 63) * 32;
  const int t   = threadIdx.x;

  // --- rope K (cos/sin from table): 8 threads/row, 8 elems each
  {
    const int r = t >> 3, p = t & 7;
    const int row = blk * 32 + r;
    const int s = row & (Ss - 1);
    const unsigned short* src = QKV + (size_t)row * NQKV + 2048 + p * 8;
    const float2* ct = ctab + s * 64 + p * 8;
    union { uint4 v; unsigned short a[8]; } lo, hi, ol, oh;
    lo.v = *(const uint4*)src;
    hi.v = *(const uint4*)(src + 64);
#pragma unroll
    for (int e = 0; e < 8; e++) {
      const float2 cs = ct[e];
      const float l = bf2f(lo.a[e]), hh = bf2f(hi.a[e]);
      ol.a[e] = f2bf(l * cs.x - hh * cs.y);
      oh.a[e] = f2bf(hh * cs.x + l * cs.y);
    }
    unsigned short* dst = Kb + (size_t)row * 128 + p * 8;
    *(uint4*)dst        = ol.v;
    *(uint4*)(dst + 64) = oh.v;
  }

  // --- stage V into LDS, s-major (32 rows x 128 cols)
#pragma unroll
  for (int c = 0; c < 2; c++) {
    const int id = c * 256 + t;
    const int vr = id >> 4, cc = id & 15;
    *(uint4*)&Vtile[vr * 136 + cc * 8] =
        *(const uint4*)(QKV + (size_t)(blk * 32 + vr) * NQKV + 2176 + cc * 8);
  }
  __syncthreads();

  // --- write Vt rows: d = t>>1 (128 dhs), half = t&1, 16 keys each
  {
    const int d = t >> 1, half = t & 1;
    union { uint4 v[2]; unsigned short a[16]; } val;
#pragma unroll
    for (int kk = 0; kk < 16; kk++)
      val.a[kk] = Vtile[(half * 16 + kk) * 136 + d];
    unsigned short* dst = Vt + ((size_t)(b * 128 + d)) * Ss + s0 + half * 16;
    *(uint4*)dst       = val.v[0];
    *(uint4*)(dst + 8) = val.v[1];
  }
}

// ---------------------------------------------------------------------------
// flash_v13 (unchanged, proven 74.1-75.0 us): paired q-tiles, 128-key
// single-buffer, slot-XOR LDS, table Q-rope, VALU diet, 512 threads / 8 waves
// (wave w<4 -> A-subtile w, w>=4 -> B-subtile w-4; K/V staging split by role).
// ---------------------------------------------------------------------------
__global__ __launch_bounds__(512, 4) void flash_v13(
    const unsigned short* __restrict__ QKV,  // (B,S,2304), q RAW (rope here)
    const unsigned short* __restrict__ Kb,   // (B,S,128) roped
    const unsigned short* __restrict__ Vt,   // (B,128,S)
    const float2* __restrict__ ctab,         // (2048, 64) cos/sin
    unsigned short* __restrict__ attn)       // (B,S,2048) bf16
{
  __shared__ unsigned short Ks[4 * 128 * 32];  // panel kf: [key128][dh32], 32 KB
  __shared__ unsigned short Vs[4 * 128 * 32];  // panel ks2: [dh128][key32], 32 KB

  // --- decode: co-resident {c, c+256} -> complementary p
  const int g  = (int)blockIdx.x;          // 0..511
  const int lo = g & 255, hi = g >> 8;
  const int p  = hi ? (15 - (lo & 15)) : (lo & 15);
  const int hb = (lo >> 4) + 16 * hi;      // 0..31
  const int h  = hb & 15;
  const int b  = hb >> 4;

  const int qA0 = (31 - p) * 64;           // heavy tile base (>= 1024)
  const int qB0 = p * 64;                  // light tile base (< 1024)

  const int tid = threadIdx.x;
  const int w = tid >> 6, lane = tid & 63;
  const int lg = lane >> 4, lm = lane & 15;

  // wave role: w<4 -> tile A subtile w; w>=4 -> tile B subtile w-4
  const bool isA = (w < 4);
  const int sw = w & 3;
  const int qt0 = isA ? qA0 : qB0;
  const int qrow    = qt0 + sw * 16 + lm;
  const int qrow_lo = qt0 + sw * 16;
  const int qrow_hi = qt0 + sw * 16 + 15;

  // swizzled frag slot: row contributions >=16 vanish mod 4 -> lane-constant
  const int klg = lg ^ ((lm >> 1) & 3);

  const float sscale = 0.08838834764831845f * 1.4426950408889634f; // /sqrt(128)*log2e

  // --- Q frag with fused table RoPE, PRE-SCALED by sscale
  bf16x8 qf[4];
  {
    union U8 { bf16x8 v; unsigned short a[8]; };
    const unsigned short* qp =
        QKV + (size_t)(b * Ss + qrow) * NQKV + h * DHd + lg * 8;
    const float2* ct = ctab + qrow * 64 + lg * 8;
    U8 lo0, lo1, hi0, hi1, ol0, ol1, oh0, oh1;
    lo0.v = *(const bf16x8*)(qp);
    lo1.v = *(const bf16x8*)(qp + 32);
    hi0.v = *(const bf16x8*)(qp + 64);
    hi1.v = *(const bf16x8*)(qp + 96);
#pragma unroll
    for (int j = 0; j < 8; j++) {
      {
        const float2 cs = ct[j];                      // i = lg*8+j
        const float l = bf2f(lo0.a[j]), hh = bf2f(hi0.a[j]);
        ol0.a[j] = f2bf((l * cs.x - hh * cs.y) * sscale);
        oh0.a[j] = f2bf((hh * cs.x + l * cs.y) * sscale);
      }
      {
        const float2 cs = ct[32 + j];                 // i = 32+lg*8+j
        const float l = bf2f(lo1.a[j]), hh = bf2f(hi1.a[j]);
        ol1.a[j] = f2bf((l * cs.x - hh * cs.y) * sscale);
        oh1.a[j] = f2bf((hh * cs.x + l * cs.y) * sscale);
      }
    }
    qf[0] = ol0.v; qf[1] = ol1.v; qf[2] = oh0.v; qf[3] = oh1.v;
  }

  // O^T accumulator, C-layout: (dh = dt*16 + 4*lg + r, qrow = lm)
  f32x4 ot[8];
#pragma unroll
  for (int dt = 0; dt < 8; dt++) ot[dt] = (f32x4){0.f, 0.f, 0.f, 0.f};
  float lsum = 0.f;

  // staging lane addresses; global chunk permuted so linear LDS dest holds
  // the slot-swizzled layout: chunk(lane) = (lane&3) ^ ((lane>>3)&3)
  const int sr  = lane >> 2;                             // row-within-16
  const int sc8 = ((lane & 3) ^ ((lane >> 3) & 3)) * 8;  // swizzled 16B chunk
  // K stager (waves 0-3): panel w = dh w*32..+31, 128 keys (8 GLOADs)
  const unsigned short* kg =
      Kb + (size_t)b * Ss * 128 + (size_t)sr * 128 + (w & 3) * 32 + sc8;
  unsigned short* ksl = &Ks[(w & 3) * 4096];
  // V stager (waves 4-7): panel ks2 = w-4 (keys ks2*32..+31), dh 0..127
  const int vks = w & 3;
  const unsigned short* vg =
      Vt + (size_t)b * 128 * Ss + (size_t)sr * Ss + sc8;
  unsigned short* vsl = &Vs[vks * 4096];

  // transpose shuffle sources (C->B layout, within a 32-key half)
  const int addr0 = (2 * (lg & 1)) * 16 + lm;   // dwords 0,1
  const int addr1 = addr0 + 16;                 // dwords 2,3
  const bool sel_hi = (lg & 2) != 0;

  // one 32-key half: S^T tiles tA,tA+1 -> exp -> transpose -> PV on panel VsP
  auto half32 = [&](int keybase, int tA, const unsigned short* VsP,
                    bool needmask) {
    f32x4 s[2];
    s[0] = (f32x4){0.f, 0.f, 0.f, 0.f};
    s[1] = (f32x4){0.f, 0.f, 0.f, 0.f};
    __builtin_amdgcn_s_setprio(1);
#pragma unroll
    for (int kf = 0; kf < 4; kf++) {
      const bf16x8 k0 = *(const bf16x8*)&Ks[kf * 4096 + ((tA)     * 16 + lm) * 32 + klg * 8];
      const bf16x8 k1 = *(const bf16x8*)&Ks[kf * 4096 + ((tA + 1) * 16 + lm) * 32 + klg * 8];
      s[0] = mfma16(k0, qf[kf], s[0]);
      s[1] = mfma16(k1, qf[kf], s[1]);
    }
    __builtin_amdgcn_s_setprio(0);
    // exp2 (max-free, Q pre-scaled) + diagonal-only mask + pack
    int pk[2][2];
#pragma unroll
    for (int t = 0; t < 2; t++) {
      float pv[4];
#pragma unroll
      for (int r = 0; r < 4; r++) pv[r] = exp2f(s[t][r]);
      if (needmask) {
        const int kb = keybase + t * 16 + 4 * lg;
#pragma unroll
        for (int r = 0; r < 4; r++)
          if (kb + r > qrow) pv[r] = 0.f;
      }
#pragma unroll
      for (int r = 0; r < 4; r++) lsum += pv[r];
      pk[t][0] = cvtpk(pv[0], pv[1]);
      pk[t][1] = cvtpk(pv[2], pv[3]);
    }
    // C-layout -> B-layout transpose (8 bpermutes)
    union { int d[4]; bf16x8 v; } pb;
#pragma unroll
    for (int d = 0; d < 4; d++) {
      const int src = (d < 2) ? addr0 : addr1;
      const int v0 = __shfl(pk[0][d & 1], src);
      const int v1 = __shfl(pk[1][d & 1], src);
      pb.d[d] = sel_hi ? v1 : v0;
    }
    // O^T += V^T(32 keys) · P^T
    __builtin_amdgcn_s_setprio(1);
#pragma unroll
    for (int dt = 0; dt < 8; dt++) {
      const bf16x8 vfrag = *(const bf16x8*)&VsP[(dt * 16 + lm) * 32 + klg * 8];
      ot[dt] = mfma16(vfrag, pb.v, ot[dt]);
    }
    __builtin_amdgcn_s_setprio(0);
  };

  for (int j0 = 0; j0 <= qA0; j0 += 128) {
    __syncthreads();            // previous iteration's LDS readers done
    if (isA) {
      // stage K panel (w&3): keys j0..j0+127, dh (w&3)*32..+31
#pragma unroll
      for (int i = 0; i < 8; i++)
        GLOAD16(kg + (size_t)(j0 + i * 16) * 128, ksl + i * 512);
    } else {
      // stage V panel vks: dh 0..127, keys j0+vks*32..+31
#pragma unroll
      for (int i = 0; i < 8; i++)
        GLOAD16(vg + (size_t)(i * 16) * Ss + j0 + vks * 32, vsl + i * 512);
    }
    __syncthreads();            // vmcnt(0) drained before use

    // my subtile: process active 32-key halves
#pragma unroll
    for (int t32 = 0; t32 < 4; t32++) {
      const int kb = j0 + t32 * 32;
      if (kb <= qrow_hi)                      // wave-uniform
        half32(kb, t32 * 2, &Vs[t32 * 4096], kb + 31 > qrow_lo);
    }
  }

  // --- epilogue: reduce lsum over the 4 lg groups, normalize, store
  lsum += __shfl_xor(lsum, 16);
  lsum += __shfl_xor(lsum, 32);
  const float inv = 1.0f / lsum;
  unsigned short* dst =
      attn + (size_t)(b * Ss + qrow) * Dd + h * DHd + lg * 4;
#pragma unroll
  for (int dt = 0; dt < 8; dt++) {
    uint2 st;
    st.x = (unsigned int)cvtpk(ot[dt][0] * inv, ot[dt][1] * inv);
    st.y = (unsigned int)cvtpk(ot[dt][2] * inv, ot[dt][3] * inv);
    *(uint2*)(dst + dt * 16) = st;
  }
}

// ---------------------------------------------------------------------------
extern "C" void kernel_launch(void* const* d_in, const int* in_sizes, int n_in,
                              void* d_out, int out_size, void* d_ws, size_t ws_size,
                              hipStream_t stream) {
  const float* x   = (const float*)d_in[0];   // (B,S,D)
  const float* qw  = (const float*)d_in[1];   // (2048, 2048)
  const float* qb  = (const float*)d_in[2];
  const float* kvw = (const float*)d_in[3];   // (256, 2048)
  const float* kvb = (const float*)d_in[4];
  const float* ow  = (const float*)d_in[5];   // (2048, 2048)
  const float* ob  = (const float*)d_in[6];
  float* out = (float*)d_out;

  // workspace layout (bf16 elements):
  //   wqkv @ 0          (2304 x 2048)   qw rows 0-2047, kvw 2048-2303
  //   owb  @ 4,718,592  (2048 x 2048)
  //   xb   @ 8,912,896  (4096 x 2048)   -> reused as attn_b
  //   QKV  @ 17,301,504 (4096 x 2304)
  //   Kb   @ 26,738,688 (4096 x 128)
  //   Vt   @ 27,262,976 (2 x 128 x 2048)
  //   ctab @ 27,787,264 (2048 x 64 float2 = 1 MB)
  unsigned short* wsb    = (unsigned short*)d_ws;
  unsigned short* wqkv   = wsb;
  unsigned short* owb    = wsb + 4718592;
  unsigned short* xb     = wsb + 8912896;
  unsigned short* attn_b = xb;                 // alias: xb dead after QKV gemm
  unsigned short* QKV    = wsb + 17301504;
  unsigned short* Kb     = wsb + 26738688;
  unsigned short* Vt     = wsb + 27262976;
  float2*         ctab   = (float2*)(wsb + 27787264);

  // 1. all fp32->bf16 casts (grid-stride, 2048 blocks) + RoPE table
  cast_all<<<2560, 256, 0, stream>>>(qw, kvw, ow, x, wqkv, ctab);

  // 2. merged QKV projection: (4096 x 2304) = xb @ wqkv^T + [qb|kvb]
  gemm_bt_mfma<true><<<dim3(NQKV / TN, BS / TM), 512, 0, stream>>>(
      xb, wqkv, qb, kvb, 2048, QKV, BS, NQKV, Dd);

  // 3. K rope (table) + V transpose (128 blocks; Q rope fused into flash)
  prep_kv<<<BS / 32, 256, 0, stream>>>(QKV, ctab, Kb, Vt);

  // 4. flash attention (8-wave pair blocks: 4 waves/SIMD)
  flash_v13<<<512, 512, 0, stream>>>(QKV, Kb, Vt, ctab, attn_b);

  // 5. O projection: out = attn @ ow^T + ob (fp32 out)
  gemm_bt_mfma<false><<<dim3(Dd / TN, BS / TM), 512, 0, stream>>>(
      attn_b, owb, ob, ob, Dd, out, BS, Dd, Dd);
}